// Round 9
// baseline (4392.096 us; speedup 1.0000x reference)
//
#include <hip/hip_runtime.h>

typedef _Float16 f16x8 __attribute__((ext_vector_type(8)));
typedef _Float16 f16x4 __attribute__((ext_vector_type(4)));
typedef float    f32x4 __attribute__((ext_vector_type(4)));

#define DEVINL __device__ __forceinline__

namespace {
constexpr int Tt = 256, Ff = 128, Hh = 256, Uu = 512, OUTo = 128;
constexpr int NCLUST = 32;               // 512 / 16 row-groups
constexpr int CBLK = 8;                  // blocks per cluster
constexpr int NSLOT = 68;                // frags per (cb,wave)
constexpr int NFRAG = CBLK * 4 * NSLOT;  // 2176
constexpr size_t WFRAG_BYTES = (size_t)NFRAG * 1024;
constexpr size_t ACT_OFF = WFRAG_BYTES;
// per cluster: z1[2][16][512] 32K | z2[2][16][512] 32K | h[2][16][256] 16K
constexpr size_t ACT_STRIDE = 81920;
constexpr size_t ACT_BYTES = (size_t)NCLUST * ACT_STRIDE;
constexpr unsigned PZ = 0x7C7C7C7Cu;     // fp16 NaN pair: never a real activation
}

// ---- weight prep: f32 row-major -> per-(cb,wave) fp16 MFMA fragment banks ----
__global__ void prep_weights(const float* __restrict__ W1, const float* __restrict__ W2,
                             const float* __restrict__ Wff1, const float* __restrict__ Wff2,
                             const float* __restrict__ Wta, const float* __restrict__ Wtb,
                             const float* __restrict__ Wout, _Float16* __restrict__ ws)
{
    int o = blockIdx.x * blockDim.x + threadIdx.x;
    if (o >= NFRAG * 512) return;
    int j = o & 7, l = (o >> 3) & 63, r = o >> 9;
    int slot = r % NSLOT, bw = r / NSLOT;
    int w = bw & 3, cb = bw >> 2;
    int k_in = ((l >> 4) << 3) + j, lc = l & 15;
    float v;
    if (slot < 12) {
        int kt = slot;
        v = W1[(kt * 32 + k_in) * Uu + cb * 64 + w * 16 + lc];
    } else if (slot < 28) {
        int kt = slot - 12;
        v = W2[(kt * 32 + k_in) * Uu + cb * 64 + w * 16 + lc];
    } else if (slot < 60) {
        int s = slot - 28, hpL = s >> 4, kt = s & 15;
        int head = (w & 1) * 2 + hpL;
        const float* W = (head == 0) ? Wff1 : (head == 1) ? Wff2 : (head == 2) ? Wta : Wtb;
        v = W[(kt * 32 + k_in) * Hh + cb * 32 + (w >> 1) * 16 + lc];
    } else {
        int kt = slot - 60;
        v = Wout[(kt * 32 + k_in) * OUTo + cb * 16 + lc];
    }
    ws[o] = (_Float16)v;
}

DEVINL float fast_tanh(float v) {
    float e = __expf(2.0f * v);
    return 1.0f - 2.0f / (e + 1.0f);
}
DEVINL float fast_sigmoid(float v) { return 1.0f / (1.0f + __expf(-v)); }
DEVINL float lecun_act(float v)    { return 1.7159f * fast_tanh(0.666f * v); }

// ---- MALL-coherent (sc0 sc1) primitives ----
DEVINL void stg8_sys(_Float16* p, f16x4 v) {
    asm volatile("global_store_dwordx2 %0, %1, off sc0 sc1" :: "v"(p), "v"(v) : "memory");
}
DEVINL void poison16(_Float16* p) {
    union { unsigned u[4]; f16x8 f; } c;
    c.u[0] = c.u[1] = c.u[2] = c.u[3] = PZ;
    asm volatile("global_store_dwordx4 %0, %1, off sc0 sc1" :: "v"(p), "v"(c.f) : "memory");
}

#define GLD4(d0, d1, d2, d3, base) \
    asm volatile( \
        "global_load_dwordx4 %0, %4, off sc0 sc1\n\t" \
        "global_load_dwordx4 %1, %4, off offset:16 sc0 sc1\n\t" \
        "global_load_dwordx4 %2, %4, off offset:32 sc0 sc1\n\t" \
        "global_load_dwordx4 %3, %4, off offset:48 sc0 sc1\n\t" \
        "s_waitcnt vmcnt(0)" \
        : "=&v"(d0), "=&v"(d1), "=&v"(d2), "=&v"(d3) : "v"(base) : "memory")

#define GLD2(d0, d1, base) \
    asm volatile( \
        "global_load_dwordx4 %0, %2, off sc0 sc1\n\t" \
        "global_load_dwordx4 %1, %2, off offset:16 sc0 sc1\n\t" \
        "s_waitcnt vmcnt(0)" \
        : "=&v"(d0), "=&v"(d1) : "v"(base) : "memory")

DEVINL unsigned chk4(int4 d) {
    return (unsigned)((d.x == (int)PZ) | (d.y == (int)PZ) | (d.z == (int)PZ) | (d.w == (int)PZ));
}
DEVINL f16x8 i2f(int4 d) {
    union { int4 i; f16x8 f; } c; c.i = d; return c.f;
}

#define MFMA16(a, b, c) __builtin_amdgcn_mfma_f32_16x16x32_f16(a, b, c, 0, 0, 0)

__global__ __launch_bounds__(256, 1)
void cfc_main(const float* __restrict__ x, const float* __restrict__ ts,
              const float* __restrict__ b1g, const float* __restrict__ b2g,
              const float* __restrict__ bff1g, const float* __restrict__ bff2g,
              const float* __restrict__ btag, const float* __restrict__ btbg,
              const float* __restrict__ boutg,
              const _Float16* __restrict__ wsf,
              char* __restrict__ actbase,
              float* __restrict__ out)
{
    __shared__ float taL[2][2][2][16][17];            // [t&1][hcol-tile][ta/tb][row][col]
    __shared__ __align__(8)  _Float16 xp[4][16][20];  // per-wave store-transpose tiles
    __shared__ __align__(16) _Float16 stg[16][520];   // staged activation tile
    __shared__ int sfl;

    const int tid = threadIdx.x;
    const int l = tid & 63, w = tid >> 6;             // 4 waves
    const int lc = l & 15, lg = l >> 4;
    const int xr = l >> 2, xs = l & 3;                // xpose readback row/seg
    const int cluster = blockIdx.x & 31;
    const int cb = blockIdx.x >> 5;
    const int r0 = cluster * 16;

    // gather-thread constants
    const int grow = tid >> 4;                        // staging row 0..15
    const int gs4 = (tid & 15) * 4;                   // z: 4 slots of 16B
    const int gs2 = (tid & 15) * 2;                   // h: 2 slots of 16B
    const int gsw = grow & 3;                         // XOR swizzle key
    const int rsw = lc & 3;                           // read-side key

    // ---- weight fragments -> registers ----
    const _Float16* wb = wsf + ((size_t)(cb * 4 + w) * NSLOT) * 512 + l * 8;
    f16x8 w1f[12], w2f[16], whf[32], wof[8];
#pragma unroll
    for (int s = 0; s < 12; ++s) w1f[s] = *(const f16x8*)(wb + s * 512);
#pragma unroll
    for (int s = 0; s < 16; ++s) w2f[s] = *(const f16x8*)(wb + (12 + s) * 512);
#pragma unroll
    for (int s = 0; s < 32; ++s) whf[s] = *(const f16x8*)(wb + (28 + s) * 512);
#pragma unroll
    for (int s = 0; s < 8; ++s)  wof[s] = *(const f16x8*)(wb + (60 + s) * 512);
#pragma unroll
    for (int s = 0; s < 12; ++s) asm volatile("" : "+v"(w1f[s]));
#pragma unroll
    for (int s = 0; s < 16; ++s) asm volatile("" : "+v"(w2f[s]));
#pragma unroll
    for (int s = 0; s < 32; ++s) asm volatile("" : "+v"(whf[s]));
#pragma unroll
    for (int s = 0; s < 8; ++s)  asm volatile("" : "+v"(wof[s]));

    // ---- per-lane biases ----
    const int colU = cb * 64 + w * 16 + lc;
    const int hcol = cb * 32 + (w >> 1) * 16 + lc;
    const int colO = cb * 16 + lc;
    const float b1c = b1g[colU], b2c = b2g[colU];
    const float bf1c = bff1g[hcol], bf2c = bff2g[hcol];
    const float btac = btag[hcol], btbc = btbg[hcol];
    const float boc = boutg[colO];

    char* act = actbase + (size_t)cluster * ACT_STRIDE;
    _Float16* z1g[2] = { (_Float16*)act,             (_Float16*)(act + 16384) };
    _Float16* z2g[2] = { (_Float16*)(act + 32768),   (_Float16*)(act + 49152) };
    _Float16* hg[2]  = { (_Float16*)(act + 65536),   (_Float16*)(act + 73728) };

    f16x8 hfrag[8];
#pragma unroll
    for (int s = 0; s < 8; ++s) hfrag[s] = f16x8{0,0,0,0,0,0,0,0};

    f16x8 xf[4];
    {
        const float* xr_ = x + ((size_t)(r0 + lc) * Tt + 0) * Ff + lg * 8;
#pragma unroll
        for (int kt = 0; kt < 4; ++kt) {
            f32x4 xa = *(const f32x4*)(xr_ + kt * 32);
            f32x4 xb = *(const f32x4*)(xr_ + kt * 32 + 4);
            f16x8 af;
#pragma unroll
            for (int q = 0; q < 4; ++q) { af[q] = (_Float16)xa[q]; af[4 + q] = (_Float16)xb[q]; }
            xf[kt] = af;
        }
    }

    for (int t = 0; t < Tt; ++t) {
        const int p = t & 1;
        _Float16* z1p = z1g[p];  _Float16* z1o = z1g[1 - p];
        _Float16* z2p = z2g[p];  _Float16* z2o = z2g[1 - p];
        _Float16* hp  = hg[p];   _Float16* ho  = hg[1 - p];

        // ---------- P1: z1 = lecun([x|h] @ W1 + b1) ----------
        {
            f32x4 a0 = {0.f,0.f,0.f,0.f}, a1 = {0.f,0.f,0.f,0.f};
            a0 = MFMA16(xf[0], w1f[0], a0);  a1 = MFMA16(xf[1], w1f[1], a1);
            a0 = MFMA16(xf[2], w1f[2], a0);  a1 = MFMA16(xf[3], w1f[3], a1);
            a0 = MFMA16(hfrag[0], w1f[4], a0);  a1 = MFMA16(hfrag[1], w1f[5], a1);
            a0 = MFMA16(hfrag[2], w1f[6], a0);  a1 = MFMA16(hfrag[3], w1f[7], a1);
            a0 = MFMA16(hfrag[4], w1f[8], a0);  a1 = MFMA16(hfrag[5], w1f[9], a1);
            a0 = MFMA16(hfrag[6], w1f[10], a0); a1 = MFMA16(hfrag[7], w1f[11], a1);
#pragma unroll
            for (int i = 0; i < 4; ++i)
                xp[w][lg * 4 + i][lc] = (_Float16)lecun_act(a0[i] + a1[i] + b1c);
            asm volatile("s_waitcnt lgkmcnt(0)" ::: "memory");
            __builtin_amdgcn_sched_barrier(0);
            f16x4 v = *(const f16x4*)&xp[w][xr][xs * 4];
            stg8_sys(z1p + xr * Uu + cb * 64 + w * 16 + xs * 4, v);
        }

        // ---------- P2: z2 = lecun(z1 @ W2 + b2) ----------
        {
            const char* gb = (const char*)z1p + tid * 64;
            int4 d0, d1, d2, d3;
            for (;;) {
                GLD4(d0, d1, d2, d3, gb);
                unsigned bad = chk4(d0) | chk4(d1) | chk4(d2) | chk4(d3);
                if (tid == 0) sfl = 0;
                __syncthreads();
                if (__any(bad)) { if (l == 0) sfl = 1; }
                __syncthreads();
                if (!sfl) break;
            }
            if (tid < 128) poison16(z1o + (2 * cb + (tid >> 6)) * Uu + (tid & 63) * 8);
            *(f16x8*)&stg[grow][((gs4 + 0) ^ gsw) * 8] = i2f(d0);
            *(f16x8*)&stg[grow][((gs4 + 1) ^ gsw) * 8] = i2f(d1);
            *(f16x8*)&stg[grow][((gs4 + 2) ^ gsw) * 8] = i2f(d2);
            *(f16x8*)&stg[grow][((gs4 + 3) ^ gsw) * 8] = i2f(d3);
            __syncthreads();
            f32x4 a0 = {0.f,0.f,0.f,0.f}, a1 = {0.f,0.f,0.f,0.f};
#pragma unroll
            for (int kt = 0; kt < 16; ++kt) {
                f16x8 zf = *(const f16x8*)&stg[lc][((kt * 4 + lg) ^ rsw) * 8];
                if (kt & 1) a1 = MFMA16(zf, w2f[kt], a1);
                else        a0 = MFMA16(zf, w2f[kt], a0);
            }
#pragma unroll
            for (int i = 0; i < 4; ++i)
                xp[w][lg * 4 + i][lc] = (_Float16)lecun_act(a0[i] + a1[i] + b2c);
            asm volatile("s_waitcnt lgkmcnt(0)" ::: "memory");
            __builtin_amdgcn_sched_barrier(0);
            f16x4 v = *(const f16x4*)&xp[w][xr][xs * 4];
            stg8_sys(z2p + xr * Uu + cb * 64 + w * 16 + xs * 4, v);
        }

        // ---------- P3: heads + gate -> h(t) ----------
        {
            const char* gb = (const char*)z2p + tid * 64;
            int4 d0, d1, d2, d3;
            for (;;) {
                GLD4(d0, d1, d2, d3, gb);
                unsigned bad = chk4(d0) | chk4(d1) | chk4(d2) | chk4(d3);
                if (tid == 0) sfl = 0;
                __syncthreads();
                if (__any(bad)) { if (l == 0) sfl = 1; }
                __syncthreads();
                if (!sfl) break;
            }
            if (tid < 128) poison16(z2o + (2 * cb + (tid >> 6)) * Uu + (tid & 63) * 8);
            *(f16x8*)&stg[grow][((gs4 + 0) ^ gsw) * 8] = i2f(d0);
            *(f16x8*)&stg[grow][((gs4 + 1) ^ gsw) * 8] = i2f(d1);
            *(f16x8*)&stg[grow][((gs4 + 2) ^ gsw) * 8] = i2f(d2);
            *(f16x8*)&stg[grow][((gs4 + 3) ^ gsw) * 8] = i2f(d3);
            __syncthreads();
            f32x4 h0 = {0.f,0.f,0.f,0.f}, h1 = {0.f,0.f,0.f,0.f};
#pragma unroll
            for (int kt = 0; kt < 16; ++kt) {
                f16x8 zf = *(const f16x8*)&stg[lc][((kt * 4 + lg) ^ rsw) * 8];
                h0 = MFMA16(zf, whf[kt], h0);
                h1 = MFMA16(zf, whf[16 + kt], h1);
            }
            if (w & 1) {          // ta, tb -> LDS (double-buffered by t parity)
#pragma unroll
                for (int i = 0; i < 4; ++i) {
                    taL[t & 1][w >> 1][0][lg * 4 + i][lc] = h0[i] + btac;
                    taL[t & 1][w >> 1][1][lg * 4 + i][lc] = h1[i] + btbc;
                }
            }
            __syncthreads();
            if (!(w & 1)) {       // ff1, ff2 + gate + h store
#pragma unroll
                for (int i = 0; i < 4; ++i) {
                    int row = lg * 4 + i;
                    float tsv = ts[(size_t)(r0 + row) * Tt + t];
                    float ff1 = fast_tanh(h0[i] + bf1c);
                    float ff2 = fast_tanh(h1[i] + bf2c);
                    float ta = taL[t & 1][w >> 1][0][row][lc];
                    float tb = taL[t & 1][w >> 1][1][row][lc];
                    float s = fast_sigmoid(ta * (tsv * (1.0f / 256.0f)) + tb);
                    xp[w][row][lc] = (_Float16)(ff1 + s * (ff2 - ff1));
                }
                asm volatile("s_waitcnt lgkmcnt(0)" ::: "memory");
                __builtin_amdgcn_sched_barrier(0);
                f16x4 v = *(const f16x4*)&xp[w][xr][xs * 4];
                stg8_sys(hp + xr * Hh + cb * 32 + (w >> 1) * 16 + xs * 4, v);
            }
        }

        // ---------- P4: gather h(t); poison h(opposite); out(t); x(t+1) ----------
        {
            f32x4 xa[4], xb[4];
            if (t + 1 < Tt) {
                const float* xr_ = x + ((size_t)(r0 + lc) * Tt + (t + 1)) * Ff + lg * 8;
#pragma unroll
                for (int kt = 0; kt < 4; ++kt) {
                    xa[kt] = *(const f32x4*)(xr_ + kt * 32);
                    xb[kt] = *(const f32x4*)(xr_ + kt * 32 + 4);
                }
            }
            const char* gb = (const char*)hp + tid * 32;
            int4 d0, d1;
            for (;;) {
                GLD2(d0, d1, gb);
                unsigned bad = chk4(d0) | chk4(d1);
                if (tid == 0) sfl = 0;
                __syncthreads();
                if (__any(bad)) { if (l == 0) sfl = 1; }
                __syncthreads();
                if (!sfl) break;
            }
            if (tid < 64) poison16(ho + (2 * cb + (tid >> 5)) * Hh + (tid & 31) * 8);
            *(f16x8*)&stg[grow][((gs2 + 0) ^ gsw) * 8] = i2f(d0);
            *(f16x8*)&stg[grow][((gs2 + 1) ^ gsw) * 8] = i2f(d1);
            __syncthreads();
#pragma unroll
            for (int kt = 0; kt < 8; ++kt)
                hfrag[kt] = *(const f16x8*)&stg[lc][((kt * 4 + lg) ^ rsw) * 8];
            if (t + 1 < Tt) {
#pragma unroll
                for (int kt = 0; kt < 4; ++kt) {
                    f16x8 af;
#pragma unroll
                    for (int q = 0; q < 4; ++q) { af[q] = (_Float16)xa[kt][q]; af[4 + q] = (_Float16)xb[kt][q]; }
                    xf[kt] = af;
                }
            }
            if (w == 0) {
                f32x4 a0 = {0.f,0.f,0.f,0.f}, a1 = {0.f,0.f,0.f,0.f};
                a0 = MFMA16(hfrag[0], wof[0], a0); a1 = MFMA16(hfrag[1], wof[1], a1);
                a0 = MFMA16(hfrag[2], wof[2], a0); a1 = MFMA16(hfrag[3], wof[3], a1);
                a0 = MFMA16(hfrag[4], wof[4], a0); a1 = MFMA16(hfrag[5], wof[5], a1);
                a0 = MFMA16(hfrag[6], wof[6], a0); a1 = MFMA16(hfrag[7], wof[7], a1);
#pragma unroll
                for (int i = 0; i < 4; ++i)
                    out[((size_t)(r0 + lg * 4 + i) * Tt + t) * OUTo + colO] = a0[i] + a1[i] + boc;
            }
        }
    }
}

extern "C" void kernel_launch(void* const* d_in, const int* in_sizes, int n_in,
                              void* d_out, int out_size, void* d_ws, size_t ws_size,
                              hipStream_t stream) {
    const float* x    = (const float*)d_in[0];
    const float* ts   = (const float*)d_in[1];
    const float* W1   = (const float*)d_in[2];
    const float* b1   = (const float*)d_in[3];
    const float* W2   = (const float*)d_in[4];
    const float* b2   = (const float*)d_in[5];
    const float* Wff1 = (const float*)d_in[6];
    const float* bff1 = (const float*)d_in[7];
    const float* Wff2 = (const float*)d_in[8];
    const float* bff2 = (const float*)d_in[9];
    const float* Wta  = (const float*)d_in[10];
    const float* bta  = (const float*)d_in[11];
    const float* Wtb  = (const float*)d_in[12];
    const float* btb  = (const float*)d_in[13];
    const float* Wout = (const float*)d_in[14];
    const float* bout = (const float*)d_in[15];
    float* out = (float*)d_out;

    _Float16* wf = (_Float16*)d_ws;
    char* act = (char*)d_ws + ACT_OFF;

    // pre-poison both parities of all exchange buffers (0x7C7C = fp16 NaN)
    hipMemsetAsync(act, 0x7C, ACT_BYTES, stream);
    prep_weights<<<(NFRAG * 512) / 256, 256, 0, stream>>>(W1, W2, Wff1, Wff2, Wta, Wtb, Wout, wf);
    cfc_main<<<NCLUST * CBLK, 256, 0, stream>>>(x, ts, b1, b2, bff1, bff2, bta, btb, bout,
                                                wf, act, out);
}

// Round 11
// 3040.052 us; speedup vs baseline: 1.4447x; 1.4447x over previous
//
#include <hip/hip_runtime.h>

typedef _Float16 f16x8 __attribute__((ext_vector_type(8)));
typedef _Float16 f16x4 __attribute__((ext_vector_type(4)));
typedef float    f32x4 __attribute__((ext_vector_type(4)));

#define DEVINL __device__ __forceinline__

namespace {
constexpr int Tt = 256, Ff = 128, Hh = 256, Uu = 512, OUTo = 128;
constexpr int NCLUST = 32;               // 512 / 16 row-groups
constexpr int CBLK = 8;                  // blocks per cluster
constexpr int NSLOT = 68;                // frags per (cb,wave): 12 W1 + 16 W2 + 32 heads + 8 Wout
constexpr int NFRAG = CBLK * 4 * NSLOT;  // 2176
constexpr size_t WFRAG_BYTES = (size_t)NFRAG * 1024;
constexpr size_t ACT_OFF = WFRAG_BYTES;
constexpr size_t ACT_STRIDE = 40960;     // z1 16K | z2 16K | h 8K (+pad)
constexpr size_t CNT_OFF = ACT_OFF + (size_t)NCLUST * ACT_STRIDE;
constexpr size_t CNT_BYTES = (size_t)NCLUST * 8 * 4;   // 8 flag slots per cluster
}

// ---- weight prep: f32 row-major -> per-(cb,wave) fp16 MFMA fragment banks ----
__global__ void prep_weights(const float* __restrict__ W1, const float* __restrict__ W2,
                             const float* __restrict__ Wff1, const float* __restrict__ Wff2,
                             const float* __restrict__ Wta, const float* __restrict__ Wtb,
                             const float* __restrict__ Wout, _Float16* __restrict__ ws)
{
    int o = blockIdx.x * blockDim.x + threadIdx.x;
    if (o >= NFRAG * 512) return;
    int j = o & 7, l = (o >> 3) & 63, r = o >> 9;
    int slot = r % NSLOT, bw = r / NSLOT;
    int w = bw & 3, cb = bw >> 2;
    int k_in = ((l >> 4) << 3) + j, lc = l & 15;
    float v;
    if (slot < 12) {
        int kt = slot;
        v = W1[(kt * 32 + k_in) * Uu + cb * 64 + w * 16 + lc];
    } else if (slot < 28) {
        int kt = slot - 12;
        v = W2[(kt * 32 + k_in) * Uu + cb * 64 + w * 16 + lc];
    } else if (slot < 60) {
        int s = slot - 28, hpL = s >> 4, kt = s & 15;
        int head = (w & 1) * 2 + hpL;
        const float* W = (head == 0) ? Wff1 : (head == 1) ? Wff2 : (head == 2) ? Wta : Wtb;
        v = W[(kt * 32 + k_in) * Hh + cb * 32 + (w >> 1) * 16 + lc];
    } else {
        int kt = slot - 60;
        v = Wout[(kt * 32 + k_in) * OUTo + cb * 16 + lc];
    }
    ws[o] = (_Float16)v;
}

DEVINL float fast_tanh(float v) {
    float e = __expf(2.0f * v);
    return 1.0f - 2.0f / (e + 1.0f);
}
DEVINL float fast_sigmoid(float v) { return 1.0f / (1.0f + __expf(-v)); }
DEVINL float lecun_act(float v)    { return 1.7159f * fast_tanh(0.666f * v); }

// ---- device-scope (sc1: cross-XCD coherent via MALL, no system path) accessors ----
DEVINL void stg8_dev(_Float16* p, f16x4 v) {
    asm volatile("global_store_dwordx2 %0, %1, off sc1" :: "v"(p), "v"(v) : "memory");
}

#define LD8_FRAGS(d, base) \
    asm volatile( \
        "global_load_dwordx4 %0, %8, off sc1\n\t" \
        "global_load_dwordx4 %1, %8, off offset:64 sc1\n\t" \
        "global_load_dwordx4 %2, %8, off offset:128 sc1\n\t" \
        "global_load_dwordx4 %3, %8, off offset:192 sc1\n\t" \
        "global_load_dwordx4 %4, %8, off offset:256 sc1\n\t" \
        "global_load_dwordx4 %5, %8, off offset:320 sc1\n\t" \
        "global_load_dwordx4 %6, %8, off offset:384 sc1\n\t" \
        "global_load_dwordx4 %7, %8, off offset:448 sc1\n\t" \
        "s_waitcnt vmcnt(0)" \
        : "=&v"(d[0]), "=&v"(d[1]), "=&v"(d[2]), "=&v"(d[3]), \
          "=&v"(d[4]), "=&v"(d[5]), "=&v"(d[6]), "=&v"(d[7]) \
        : "v"(base) : "memory")

#define LD16_FRAGS(d, base) \
    asm volatile( \
        "global_load_dwordx4 %0, %16, off sc1\n\t" \
        "global_load_dwordx4 %1, %16, off offset:64 sc1\n\t" \
        "global_load_dwordx4 %2, %16, off offset:128 sc1\n\t" \
        "global_load_dwordx4 %3, %16, off offset:192 sc1\n\t" \
        "global_load_dwordx4 %4, %16, off offset:256 sc1\n\t" \
        "global_load_dwordx4 %5, %16, off offset:320 sc1\n\t" \
        "global_load_dwordx4 %6, %16, off offset:384 sc1\n\t" \
        "global_load_dwordx4 %7, %16, off offset:448 sc1\n\t" \
        "global_load_dwordx4 %8, %16, off offset:512 sc1\n\t" \
        "global_load_dwordx4 %9, %16, off offset:576 sc1\n\t" \
        "global_load_dwordx4 %10, %16, off offset:640 sc1\n\t" \
        "global_load_dwordx4 %11, %16, off offset:704 sc1\n\t" \
        "global_load_dwordx4 %12, %16, off offset:768 sc1\n\t" \
        "global_load_dwordx4 %13, %16, off offset:832 sc1\n\t" \
        "global_load_dwordx4 %14, %16, off offset:896 sc1\n\t" \
        "global_load_dwordx4 %15, %16, off offset:960 sc1\n\t" \
        "s_waitcnt vmcnt(0)" \
        : "=&v"(d[0]), "=&v"(d[1]), "=&v"(d[2]), "=&v"(d[3]), \
          "=&v"(d[4]), "=&v"(d[5]), "=&v"(d[6]), "=&v"(d[7]), \
          "=&v"(d[8]), "=&v"(d[9]), "=&v"(d[10]), "=&v"(d[11]), \
          "=&v"(d[12]), "=&v"(d[13]), "=&v"(d[14]), "=&v"(d[15]) \
        : "v"(base) : "memory")

#define MFMA16(a, b, c) __builtin_amdgcn_mfma_f32_16x16x32_f16(a, b, c, 0, 0, 0)

// arrive: drain all my stores, block-sync, thread0 publishes monotone tag (device scope)
DEVINL void arrive(int* flags, int cb, int tag, int tid) {
    asm volatile("s_waitcnt vmcnt(0)" ::: "memory");
    __syncthreads();
    if (tid == 0)
        asm volatile("global_store_dword %0, %1, off sc1" :: "v"(flags + cb), "v"(tag) : "memory");
}
// wait: thread0 polls all 8 flags >= tag
DEVINL void waitf(int* flags, int tag, int tid) {
    if (tid == 0) {
        for (;;) {
            int4 a, b;
            asm volatile("global_load_dwordx4 %0, %2, off sc1\n\t"
                         "global_load_dwordx4 %1, %2, off offset:16 sc1\n\t"
                         "s_waitcnt vmcnt(0)"
                         : "=&v"(a), "=&v"(b) : "v"(flags) : "memory");
            int m0 = min(min(a.x, a.y), min(a.z, a.w));
            int m1 = min(min(b.x, b.y), min(b.z, b.w));
            if (min(m0, m1) >= tag) break;
        }
    }
    __syncthreads();
    __builtin_amdgcn_sched_barrier(0);
}

__global__ __launch_bounds__(256, 1)
void cfc_main(const float* __restrict__ x, const float* __restrict__ ts,
              const float* __restrict__ b1g, const float* __restrict__ b2g,
              const float* __restrict__ bff1g, const float* __restrict__ bff2g,
              const float* __restrict__ btag, const float* __restrict__ btbg,
              const float* __restrict__ boutg,
              const _Float16* __restrict__ wsf,
              char* __restrict__ actbase, int* __restrict__ cntbase,
              float* __restrict__ out)
{
    __shared__ float taL[2][2][2][16][17];            // [t&1][hcol-tile][ta/tb][row][col]
    __shared__ __align__(8) _Float16 xp[4][16][20];   // per-wave transpose tiles

    const int tid = threadIdx.x;
    const int l = tid & 63, w = tid >> 6;             // 4 waves
    const int lc = l & 15, lg = l >> 4;
    const int xr = l >> 2, xs = l & 3;                // xpose readback row/seg
    const int cluster = blockIdx.x & 31;
    const int cb = blockIdx.x >> 5;
    const int r0 = cluster * 16;

    // ---- weight fragments -> registers ----
    const _Float16* wb = wsf + ((size_t)(cb * 4 + w) * NSLOT) * 512 + l * 8;
    f16x8 w1f[12], w2f[16], whf[32], wof[8];
#pragma unroll
    for (int s = 0; s < 12; ++s) w1f[s] = *(const f16x8*)(wb + s * 512);
#pragma unroll
    for (int s = 0; s < 16; ++s) w2f[s] = *(const f16x8*)(wb + (12 + s) * 512);
#pragma unroll
    for (int s = 0; s < 32; ++s) whf[s] = *(const f16x8*)(wb + (28 + s) * 512);
#pragma unroll
    for (int s = 0; s < 8; ++s)  wof[s] = *(const f16x8*)(wb + (60 + s) * 512);

    // ---- per-lane biases ----
    const int colU = cb * 64 + w * 16 + lc;
    const int hcol = cb * 32 + (w >> 1) * 16 + lc;
    const int colO = cb * 16 + lc;
    const float b1c = b1g[colU], b2c = b2g[colU];
    const float bf1c = bff1g[hcol], bf2c = bff2g[hcol];
    const float btac = btag[hcol], btbc = btbg[hcol];
    const float boc = boutg[colO];

    char* act = actbase + (size_t)cluster * ACT_STRIDE;
    _Float16* z1g = (_Float16*)act;               // [16][512]
    _Float16* z2g = (_Float16*)(act + 16384);     // [16][512]
    _Float16* hg  = (_Float16*)(act + 32768);     // [16][256]
    int* flags = cntbase + cluster * 8;

    f16x8 hfrag[8];
#pragma unroll
    for (int s = 0; s < 8; ++s) hfrag[s] = f16x8{0,0,0,0,0,0,0,0};

    f16x8 xf[4];
    {
        const float* xr_ = x + ((size_t)(r0 + lc) * Tt + 0) * Ff + lg * 8;
#pragma unroll
        for (int kt = 0; kt < 4; ++kt) {
            f32x4 xa = *(const f32x4*)(xr_ + kt * 32);
            f32x4 xb = *(const f32x4*)(xr_ + kt * 32 + 4);
            f16x8 af;
#pragma unroll
            for (int q = 0; q < 4; ++q) { af[q] = (_Float16)xa[q]; af[4 + q] = (_Float16)xb[q]; }
            xf[kt] = af;
        }
    }

    for (int t = 0; t < Tt; ++t) {
        // ---- pin weights resident across the iteration ----
#pragma unroll
        for (int s = 0; s < 12; ++s) asm volatile("" : "+v"(w1f[s]));
#pragma unroll
        for (int s = 0; s < 16; ++s) asm volatile("" : "+v"(w2f[s]));
#pragma unroll
        for (int s = 0; s < 32; ++s) asm volatile("" : "+v"(whf[s]));
#pragma unroll
        for (int s = 0; s < 8; ++s)  asm volatile("" : "+v"(wof[s]));

        // ---------- P1: z1 = lecun([x|h] @ W1 + b1) ----------
        {
            f32x4 a0 = {0.f,0.f,0.f,0.f}, a1 = {0.f,0.f,0.f,0.f};
            a0 = MFMA16(xf[0], w1f[0], a0);  a1 = MFMA16(xf[1], w1f[1], a1);
            a0 = MFMA16(xf[2], w1f[2], a0);  a1 = MFMA16(xf[3], w1f[3], a1);
            a0 = MFMA16(hfrag[0], w1f[4], a0);  a1 = MFMA16(hfrag[1], w1f[5], a1);
            a0 = MFMA16(hfrag[2], w1f[6], a0);  a1 = MFMA16(hfrag[3], w1f[7], a1);
            a0 = MFMA16(hfrag[4], w1f[8], a0);  a1 = MFMA16(hfrag[5], w1f[9], a1);
            a0 = MFMA16(hfrag[6], w1f[10], a0); a1 = MFMA16(hfrag[7], w1f[11], a1);
#pragma unroll
            for (int i = 0; i < 4; ++i)
                xp[w][lg * 4 + i][lc] = (_Float16)lecun_act(a0[i] + a1[i] + b1c);
            asm volatile("s_waitcnt lgkmcnt(0)" ::: "memory");
            __builtin_amdgcn_sched_barrier(0);
            f16x4 v = *(const f16x4*)&xp[w][xr][xs * 4];
            stg8_dev(z1g + xr * Uu + cb * 64 + w * 16 + xs * 4, v);
        }
        arrive(flags, cb, 3 * t + 1, tid);

        // ---------- P2: z2 = lecun(z1 @ W2 + b2) ----------
        waitf(flags, 3 * t + 1, tid);
        {
            f16x8 zf[16];
            LD16_FRAGS(zf, z1g + lc * Uu + lg * 8);
            f32x4 a0 = {0.f,0.f,0.f,0.f}, a1 = {0.f,0.f,0.f,0.f};
#pragma unroll
            for (int kt = 0; kt < 16; ++kt) {
                if (kt & 1) a1 = MFMA16(zf[kt], w2f[kt], a1);
                else        a0 = MFMA16(zf[kt], w2f[kt], a0);
            }
#pragma unroll
            for (int i = 0; i < 4; ++i)
                xp[w][lg * 4 + i][lc] = (_Float16)lecun_act(a0[i] + a1[i] + b2c);
            asm volatile("s_waitcnt lgkmcnt(0)" ::: "memory");
            __builtin_amdgcn_sched_barrier(0);
            f16x4 v = *(const f16x4*)&xp[w][xr][xs * 4];
            stg8_dev(z2g + xr * Uu + cb * 64 + w * 16 + xs * 4, v);
        }
        arrive(flags, cb, 3 * t + 2, tid);

        // ---------- P3: heads + gate -> h(t) ----------
        waitf(flags, 3 * t + 2, tid);
        {
            f16x8 zf[16];
            LD16_FRAGS(zf, z2g + lc * Uu + lg * 8);
            f32x4 h0 = {0.f,0.f,0.f,0.f}, h1 = {0.f,0.f,0.f,0.f};
#pragma unroll
            for (int kt = 0; kt < 16; ++kt) {
                h0 = MFMA16(zf[kt], whf[kt], h0);
                h1 = MFMA16(zf[kt], whf[16 + kt], h1);
            }
            if (w & 1) {          // heads 2,3 = ta, tb -> LDS (parity double-buffered)
#pragma unroll
                for (int i = 0; i < 4; ++i) {
                    taL[t & 1][w >> 1][0][lg * 4 + i][lc] = h0[i] + btac;
                    taL[t & 1][w >> 1][1][lg * 4 + i][lc] = h1[i] + btbc;
                }
            }
            __syncthreads();
            if (!(w & 1)) {       // heads 0,1 = ff1, ff2 + gate + h store
#pragma unroll
                for (int i = 0; i < 4; ++i) {
                    int row = lg * 4 + i;
                    float tsv = ts[(size_t)(r0 + row) * Tt + t];
                    float ff1 = fast_tanh(h0[i] + bf1c);
                    float ff2 = fast_tanh(h1[i] + bf2c);
                    float ta = taL[t & 1][w >> 1][0][row][lc];
                    float tb = taL[t & 1][w >> 1][1][row][lc];
                    float s = fast_sigmoid(ta * (tsv * (1.0f / 256.0f)) + tb);
                    xp[w][row][lc] = (_Float16)(ff1 + s * (ff2 - ff1));
                }
                asm volatile("s_waitcnt lgkmcnt(0)" ::: "memory");
                __builtin_amdgcn_sched_barrier(0);
                f16x4 v = *(const f16x4*)&xp[w][xr][xs * 4];
                stg8_dev(hg + xr * Hh + cb * 32 + (w >> 1) * 16 + xs * 4, v);
            }
        }
        arrive(flags, cb, 3 * t + 3, tid);

        // ---------- P4: h gather; x(t+1) prefetch; out(t) ----------
        waitf(flags, 3 * t + 3, tid);
        {
            f32x4 xa[4], xb[4];
            if (t + 1 < Tt) {
                const float* xr_ = x + ((size_t)(r0 + lc) * Tt + (t + 1)) * Ff + lg * 8;
#pragma unroll
                for (int kt = 0; kt < 4; ++kt) {
                    xa[kt] = *(const f32x4*)(xr_ + kt * 32);
                    xb[kt] = *(const f32x4*)(xr_ + kt * 32 + 4);
                }
            }
            LD8_FRAGS(hfrag, hg + lc * Hh + lg * 8);
            if (t + 1 < Tt) {
#pragma unroll
                for (int kt = 0; kt < 4; ++kt) {
                    f16x8 af;
#pragma unroll
                    for (int q = 0; q < 4; ++q) { af[q] = (_Float16)xa[kt][q]; af[4 + q] = (_Float16)xb[kt][q]; }
                    xf[kt] = af;
                }
            }
            if (w == 0) {
                f32x4 a0 = {0.f,0.f,0.f,0.f}, a1 = {0.f,0.f,0.f,0.f};
                a0 = MFMA16(hfrag[0], wof[0], a0); a1 = MFMA16(hfrag[1], wof[1], a1);
                a0 = MFMA16(hfrag[2], wof[2], a0); a1 = MFMA16(hfrag[3], wof[3], a1);
                a0 = MFMA16(hfrag[4], wof[4], a0); a1 = MFMA16(hfrag[5], wof[5], a1);
                a0 = MFMA16(hfrag[6], wof[6], a0); a1 = MFMA16(hfrag[7], wof[7], a1);
#pragma unroll
                for (int i = 0; i < 4; ++i)
                    out[((size_t)(r0 + lg * 4 + i) * Tt + t) * OUTo + colO] = a0[i] + a1[i] + boc;
            }
        }
    }
}

extern "C" void kernel_launch(void* const* d_in, const int* in_sizes, int n_in,
                              void* d_out, int out_size, void* d_ws, size_t ws_size,
                              hipStream_t stream) {
    const float* x    = (const float*)d_in[0];
    const float* ts   = (const float*)d_in[1];
    const float* W1   = (const float*)d_in[2];
    const float* b1   = (const float*)d_in[3];
    const float* W2   = (const float*)d_in[4];
    const float* b2   = (const float*)d_in[5];
    const float* Wff1 = (const float*)d_in[6];
    const float* bff1 = (const float*)d_in[7];
    const float* Wff2 = (const float*)d_in[8];
    const float* bff2 = (const float*)d_in[9];
    const float* Wta  = (const float*)d_in[10];
    const float* bta  = (const float*)d_in[11];
    const float* Wtb  = (const float*)d_in[12];
    const float* btb  = (const float*)d_in[13];
    const float* Wout = (const float*)d_in[14];
    const float* bout = (const float*)d_in[15];
    float* out = (float*)d_out;

    _Float16* wf = (_Float16*)d_ws;
    char* act = (char*)d_ws + ACT_OFF;
    int* cnt = (int*)((char*)d_ws + CNT_OFF);

    hipMemsetAsync(cnt, 0, CNT_BYTES, stream);
    prep_weights<<<(NFRAG * 512) / 256, 256, 0, stream>>>(W1, W2, Wff1, Wff2, Wta, Wtb, Wout, wf);
    cfc_main<<<NCLUST * CBLK, 256, 0, stream>>>(x, ts, b1, b2, bff1, bff2, bta, btb, bout,
                                                wf, act, cnt, out);
}

// Round 14
// 2849.684 us; speedup vs baseline: 1.5413x; 1.0668x over previous
//
#include <hip/hip_runtime.h>

typedef _Float16 f16x8 __attribute__((ext_vector_type(8)));
typedef _Float16 f16x4 __attribute__((ext_vector_type(4)));
typedef float    f32x4 __attribute__((ext_vector_type(4)));

#define DEVINL __device__ __forceinline__

namespace {
constexpr int Tt = 256, Ff = 128, Hh = 256, Uu = 512, OUTo = 128;
constexpr int NCLUST = 32;               // 512 / 16 row-groups
constexpr int CBLK = 8;                  // blocks per cluster
constexpr int NSLOT = 68;                // frags per (cb,wave): 12 W1 + 16 W2 + 32 heads + 8 Wout
constexpr int NFRAG = CBLK * 4 * NSLOT;  // 2176
constexpr size_t WFRAG_BYTES = (size_t)NFRAG * 1024;
constexpr size_t ACT_OFF = WFRAG_BYTES;
constexpr size_t ACT_STRIDE = 40960;     // z1 16K | z2 16K | h 8K (+pad)
constexpr size_t CNT_OFF = ACT_OFF + (size_t)NCLUST * ACT_STRIDE;
constexpr size_t CNT_BYTES = (size_t)NCLUST * 8 * 4;   // 8 flag slots per cluster
}

// ---- weight prep: f32 row-major -> per-(cb,wave) fp16 MFMA fragment banks ----
__global__ void prep_weights(const float* __restrict__ W1, const float* __restrict__ W2,
                             const float* __restrict__ Wff1, const float* __restrict__ Wff2,
                             const float* __restrict__ Wta, const float* __restrict__ Wtb,
                             const float* __restrict__ Wout, _Float16* __restrict__ ws)
{
    int o = blockIdx.x * blockDim.x + threadIdx.x;
    if (o >= NFRAG * 512) return;
    int j = o & 7, l = (o >> 3) & 63, r = o >> 9;
    int slot = r % NSLOT, bw = r / NSLOT;
    int w = bw & 3, cb = bw >> 2;
    int k_in = ((l >> 4) << 3) + j, lc = l & 15;
    float v;
    if (slot < 12) {
        int kt = slot;
        v = W1[(kt * 32 + k_in) * Uu + cb * 64 + w * 16 + lc];
    } else if (slot < 28) {
        int kt = slot - 12;
        v = W2[(kt * 32 + k_in) * Uu + cb * 64 + w * 16 + lc];
    } else if (slot < 60) {
        int s = slot - 28, hpL = s >> 4, kt = s & 15;
        int head = (w & 1) * 2 + hpL;
        const float* W = (head == 0) ? Wff1 : (head == 1) ? Wff2 : (head == 2) ? Wta : Wtb;
        v = W[(kt * 32 + k_in) * Hh + cb * 32 + (w >> 1) * 16 + lc];
    } else {
        int kt = slot - 60;
        v = Wout[(kt * 32 + k_in) * OUTo + cb * 16 + lc];
    }
    ws[o] = (_Float16)v;
}

DEVINL float fast_tanh(float v) {
    float e = __expf(2.0f * v);
    return 1.0f - 2.0f / (e + 1.0f);
}
DEVINL float fast_sigmoid(float v) { return 1.0f / (1.0f + __expf(-v)); }
DEVINL float lecun_act(float v)    { return 1.7159f * fast_tanh(0.666f * v); }

// ---- device-scope (sc1) accessors ----
DEVINL void stg8_dev(_Float16* p, f16x4 v) {
    asm volatile("global_store_dwordx2 %0, %1, off sc1" :: "v"(p), "v"(v) : "memory");
}

#define LD8_FRAGS(d, base) \
    asm volatile( \
        "global_load_dwordx4 %0, %8, off sc1\n\t" \
        "global_load_dwordx4 %1, %8, off offset:64 sc1\n\t" \
        "global_load_dwordx4 %2, %8, off offset:128 sc1\n\t" \
        "global_load_dwordx4 %3, %8, off offset:192 sc1\n\t" \
        "global_load_dwordx4 %4, %8, off offset:256 sc1\n\t" \
        "global_load_dwordx4 %5, %8, off offset:320 sc1\n\t" \
        "global_load_dwordx4 %6, %8, off offset:384 sc1\n\t" \
        "global_load_dwordx4 %7, %8, off offset:448 sc1\n\t" \
        "s_waitcnt vmcnt(0)" \
        : "=&v"(d[0]), "=&v"(d[1]), "=&v"(d[2]), "=&v"(d[3]), \
          "=&v"(d[4]), "=&v"(d[5]), "=&v"(d[6]), "=&v"(d[7]) \
        : "v"(base) : "memory")

#define LD16_FRAGS(d, base) \
    asm volatile( \
        "global_load_dwordx4 %0, %16, off sc1\n\t" \
        "global_load_dwordx4 %1, %16, off offset:64 sc1\n\t" \
        "global_load_dwordx4 %2, %16, off offset:128 sc1\n\t" \
        "global_load_dwordx4 %3, %16, off offset:192 sc1\n\t" \
        "global_load_dwordx4 %4, %16, off offset:256 sc1\n\t" \
        "global_load_dwordx4 %5, %16, off offset:320 sc1\n\t" \
        "global_load_dwordx4 %6, %16, off offset:384 sc1\n\t" \
        "global_load_dwordx4 %7, %16, off offset:448 sc1\n\t" \
        "global_load_dwordx4 %8, %16, off offset:512 sc1\n\t" \
        "global_load_dwordx4 %9, %16, off offset:576 sc1\n\t" \
        "global_load_dwordx4 %10, %16, off offset:640 sc1\n\t" \
        "global_load_dwordx4 %11, %16, off offset:704 sc1\n\t" \
        "global_load_dwordx4 %12, %16, off offset:768 sc1\n\t" \
        "global_load_dwordx4 %13, %16, off offset:832 sc1\n\t" \
        "global_load_dwordx4 %14, %16, off offset:896 sc1\n\t" \
        "global_load_dwordx4 %15, %16, off offset:960 sc1\n\t" \
        "s_waitcnt vmcnt(0)" \
        : "=&v"(d[0]), "=&v"(d[1]), "=&v"(d[2]), "=&v"(d[3]), \
          "=&v"(d[4]), "=&v"(d[5]), "=&v"(d[6]), "=&v"(d[7]), \
          "=&v"(d[8]), "=&v"(d[9]), "=&v"(d[10]), "=&v"(d[11]), \
          "=&v"(d[12]), "=&v"(d[13]), "=&v"(d[14]), "=&v"(d[15]) \
        : "v"(base) : "memory")

#define MFMA16(a, b, c) __builtin_amdgcn_mfma_f32_16x16x32_f16(a, b, c, 0, 0, 0)

// arrive: drain all my stores, block-sync, thread0 publishes monotone tag (device scope)
DEVINL void arrive(int* flags, int cb, int tag, int tid) {
    asm volatile("s_waitcnt vmcnt(0)" ::: "memory");
    __syncthreads();
    if (tid == 0)
        asm volatile("global_store_dword %0, %1, off sc1" :: "v"(flags + cb), "v"(tag) : "memory");
}
// wait: thread0 polls all 8 flags >= tag
DEVINL void waitf(int* flags, int tag, int tid) {
    if (tid == 0) {
        for (;;) {
            int4 a, b;
            asm volatile("global_load_dwordx4 %0, %2, off sc1\n\t"
                         "global_load_dwordx4 %1, %2, off offset:16 sc1\n\t"
                         "s_waitcnt vmcnt(0)"
                         : "=&v"(a), "=&v"(b) : "v"(flags) : "memory");
            int m0 = min(min(a.x, a.y), min(a.z, a.w));
            int m1 = min(min(b.x, b.y), min(b.z, b.w));
            if (min(m0, m1) >= tag) break;
        }
    }
    __syncthreads();
    __builtin_amdgcn_sched_barrier(0);
}

__global__ __launch_bounds__(256, 1)
void cfc_main(const float* __restrict__ x, const float* __restrict__ ts,
              const float* __restrict__ b1g, const float* __restrict__ b2g,
              const float* __restrict__ bff1g, const float* __restrict__ bff2g,
              const float* __restrict__ btag, const float* __restrict__ btbg,
              const float* __restrict__ boutg,
              const _Float16* __restrict__ wsf,
              char* __restrict__ actbase, int* __restrict__ cntbase,
              float* __restrict__ out)
{
    __shared__ float taL[2][2][2][16][17];            // [t&1][hcol-tile][ta/tb][row][col]
    __shared__ __align__(8) _Float16 xp[4][16][20];   // per-wave transpose tiles

    const int tid = threadIdx.x;
    const int l = tid & 63, w = tid >> 6;             // 4 waves
    const int lc = l & 15, lg = l >> 4;
    const int xr = l >> 2, xs = l & 3;                // xpose readback row/seg
    const int cluster = blockIdx.x & 31;
    const int cb = blockIdx.x >> 5;
    const int r0 = cluster * 16;

    // ---- weight fragments -> registers ----
    // w1f/w2f (28 frags = 112 regs) live in arch VGPRs ("v"); whf/wof (40 frags =
    // 160 regs) are pinned to AGPRs ("a") — gfx950 MFMA reads B-operands from
    // AGPRs directly, and the 256-entry arch file cannot hold all 272.
    const _Float16* wb = wsf + ((size_t)(cb * 4 + w) * NSLOT) * 512 + l * 8;
    f16x8 w1f[12], w2f[16], whf[32], wof[8];
#pragma unroll
    for (int s = 0; s < 12; ++s) w1f[s] = *(const f16x8*)(wb + s * 512);
#pragma unroll
    for (int s = 0; s < 16; ++s) w2f[s] = *(const f16x8*)(wb + (12 + s) * 512);
#pragma unroll
    for (int s = 0; s < 32; ++s) whf[s] = *(const f16x8*)(wb + (28 + s) * 512);
#pragma unroll
    for (int s = 0; s < 8; ++s)  wof[s] = *(const f16x8*)(wb + (60 + s) * 512);

    // ---- per-lane biases ----
    const int colU = cb * 64 + w * 16 + lc;
    const int hcol = cb * 32 + (w >> 1) * 16 + lc;
    const int colO = cb * 16 + lc;
    const float b1c = b1g[colU], b2c = b2g[colU];
    const float bf1c = bff1g[hcol], bf2c = bff2g[hcol];
    const float btac = btag[hcol], btbc = btbg[hcol];
    const float boc = boutg[colO];

    char* act = actbase + (size_t)cluster * ACT_STRIDE;
    _Float16* z1g = (_Float16*)act;               // [16][512]
    _Float16* z2g = (_Float16*)(act + 16384);     // [16][512]
    _Float16* hg  = (_Float16*)(act + 32768);     // [16][256]
    int* flags = cntbase + cluster * 8;

    f16x8 hfrag[8];
#pragma unroll
    for (int s = 0; s < 8; ++s) hfrag[s] = f16x8{0,0,0,0,0,0,0,0};

    f16x8 xf[4];
    {
        const float* xr_ = x + ((size_t)(r0 + lc) * Tt + 0) * Ff + lg * 8;
#pragma unroll
        for (int kt = 0; kt < 4; ++kt) {
            f32x4 xa = *(const f32x4*)(xr_ + kt * 32);
            f32x4 xb = *(const f32x4*)(xr_ + kt * 32 + 4);
            f16x8 af;
#pragma unroll
            for (int q = 0; q < 4; ++q) { af[q] = (_Float16)xa[q]; af[4 + q] = (_Float16)xb[q]; }
            xf[kt] = af;
        }
    }

    for (int t = 0; t < Tt; ++t) {
        // ---- pin weights resident: arch VGPRs for W1/W2, AGPRs for heads/out ----
#pragma unroll
        for (int s = 0; s < 12; ++s) asm volatile("" : "+v"(w1f[s]));
#pragma unroll
        for (int s = 0; s < 16; ++s) asm volatile("" : "+v"(w2f[s]));
#pragma unroll
        for (int s = 0; s < 32; ++s) asm volatile("" : "+a"(whf[s]));
#pragma unroll
        for (int s = 0; s < 8; ++s)  asm volatile("" : "+a"(wof[s]));

        // ---------- P1: z1 = lecun([x|h] @ W1 + b1) ----------
        {
            f32x4 a0 = {0.f,0.f,0.f,0.f}, a1 = {0.f,0.f,0.f,0.f};
            a0 = MFMA16(xf[0], w1f[0], a0);  a1 = MFMA16(xf[1], w1f[1], a1);
            a0 = MFMA16(xf[2], w1f[2], a0);  a1 = MFMA16(xf[3], w1f[3], a1);
            a0 = MFMA16(hfrag[0], w1f[4], a0);  a1 = MFMA16(hfrag[1], w1f[5], a1);
            a0 = MFMA16(hfrag[2], w1f[6], a0);  a1 = MFMA16(hfrag[3], w1f[7], a1);
            a0 = MFMA16(hfrag[4], w1f[8], a0);  a1 = MFMA16(hfrag[5], w1f[9], a1);
            a0 = MFMA16(hfrag[6], w1f[10], a0); a1 = MFMA16(hfrag[7], w1f[11], a1);
#pragma unroll
            for (int i = 0; i < 4; ++i)
                xp[w][lg * 4 + i][lc] = (_Float16)lecun_act(a0[i] + a1[i] + b1c);
            asm volatile("s_waitcnt lgkmcnt(0)" ::: "memory");
            __builtin_amdgcn_sched_barrier(0);
            f16x4 v = *(const f16x4*)&xp[w][xr][xs * 4];
            stg8_dev(z1g + xr * Uu + cb * 64 + w * 16 + xs * 4, v);
        }
        arrive(flags, cb, 3 * t + 1, tid);

        // ---------- P2: z2 = lecun(z1 @ W2 + b2) ----------
        waitf(flags, 3 * t + 1, tid);
        {
            f16x8 zf[16];
            LD16_FRAGS(zf, z1g + lc * Uu + lg * 8);
            f32x4 a0 = {0.f,0.f,0.f,0.f}, a1 = {0.f,0.f,0.f,0.f};
#pragma unroll
            for (int kt = 0; kt < 16; ++kt) {
                if (kt & 1) a1 = MFMA16(zf[kt], w2f[kt], a1);
                else        a0 = MFMA16(zf[kt], w2f[kt], a0);
            }
#pragma unroll
            for (int i = 0; i < 4; ++i)
                xp[w][lg * 4 + i][lc] = (_Float16)lecun_act(a0[i] + a1[i] + b2c);
            asm volatile("s_waitcnt lgkmcnt(0)" ::: "memory");
            __builtin_amdgcn_sched_barrier(0);
            f16x4 v = *(const f16x4*)&xp[w][xr][xs * 4];
            stg8_dev(z2g + xr * Uu + cb * 64 + w * 16 + xs * 4, v);
        }
        arrive(flags, cb, 3 * t + 2, tid);

        // ---------- P3: heads + gate -> h(t) ----------
        waitf(flags, 3 * t + 2, tid);
        {
            f16x8 zf[16];
            LD16_FRAGS(zf, z2g + lc * Uu + lg * 8);
            f32x4 h0 = {0.f,0.f,0.f,0.f}, h1 = {0.f,0.f,0.f,0.f};
#pragma unroll
            for (int kt = 0; kt < 16; ++kt) {
                h0 = MFMA16(zf[kt], whf[kt], h0);
                h1 = MFMA16(zf[kt], whf[16 + kt], h1);
            }
            if (w & 1) {          // heads 2,3 = ta, tb -> LDS (parity double-buffered)
#pragma unroll
                for (int i = 0; i < 4; ++i) {
                    taL[t & 1][w >> 1][0][lg * 4 + i][lc] = h0[i] + btac;
                    taL[t & 1][w >> 1][1][lg * 4 + i][lc] = h1[i] + btbc;
                }
            }
            __syncthreads();
            if (!(w & 1)) {       // heads 0,1 = ff1, ff2 + gate + h store
#pragma unroll
                for (int i = 0; i < 4; ++i) {
                    int row = lg * 4 + i;
                    float tsv = ts[(size_t)(r0 + row) * Tt + t];
                    float ff1 = fast_tanh(h0[i] + bf1c);
                    float ff2 = fast_tanh(h1[i] + bf2c);
                    float ta = taL[t & 1][w >> 1][0][row][lc];
                    float tb = taL[t & 1][w >> 1][1][row][lc];
                    float s = fast_sigmoid(ta * (tsv * (1.0f / 256.0f)) + tb);
                    xp[w][row][lc] = (_Float16)(ff1 + s * (ff2 - ff1));
                }
                asm volatile("s_waitcnt lgkmcnt(0)" ::: "memory");
                __builtin_amdgcn_sched_barrier(0);
                f16x4 v = *(const f16x4*)&xp[w][xr][xs * 4];
                stg8_dev(hg + xr * Hh + cb * 32 + (w >> 1) * 16 + xs * 4, v);
            }
        }
        arrive(flags, cb, 3 * t + 3, tid);

        // ---------- P4: h gather; x(t+1) prefetch; out(t) ----------
        waitf(flags, 3 * t + 3, tid);
        {
            f32x4 xa[4], xb[4];
            if (t + 1 < Tt) {
                const float* xr_ = x + ((size_t)(r0 + lc) * Tt + (t + 1)) * Ff + lg * 8;
#pragma unroll
                for (int kt = 0; kt < 4; ++kt) {
                    xa[kt] = *(const f32x4*)(xr_ + kt * 32);
                    xb[kt] = *(const f32x4*)(xr_ + kt * 32 + 4);
                }
            }
            LD8_FRAGS(hfrag, hg + lc * Hh + lg * 8);
            if (t + 1 < Tt) {
#pragma unroll
                for (int kt = 0; kt < 4; ++kt) {
                    f16x8 af;
#pragma unroll
                    for (int q = 0; q < 4; ++q) { af[q] = (_Float16)xa[kt][q]; af[4 + q] = (_Float16)xb[kt][q]; }
                    xf[kt] = af;
                }
            }
            if (w == 0) {
                f32x4 a0 = {0.f,0.f,0.f,0.f}, a1 = {0.f,0.f,0.f,0.f};
                a0 = MFMA16(hfrag[0], wof[0], a0); a1 = MFMA16(hfrag[1], wof[1], a1);
                a0 = MFMA16(hfrag[2], wof[2], a0); a1 = MFMA16(hfrag[3], wof[3], a1);
                a0 = MFMA16(hfrag[4], wof[4], a0); a1 = MFMA16(hfrag[5], wof[5], a1);
                a0 = MFMA16(hfrag[6], wof[6], a0); a1 = MFMA16(hfrag[7], wof[7], a1);
#pragma unroll
                for (int i = 0; i < 4; ++i)
                    out[((size_t)(r0 + lg * 4 + i) * Tt + t) * OUTo + colO] = a0[i] + a1[i] + boc;
            }
        }
    }
}

extern "C" void kernel_launch(void* const* d_in, const int* in_sizes, int n_in,
                              void* d_out, int out_size, void* d_ws, size_t ws_size,
                              hipStream_t stream) {
    const float* x    = (const float*)d_in[0];
    const float* ts   = (const float*)d_in[1];
    const float* W1   = (const float*)d_in[2];
    const float* b1   = (const float*)d_in[3];
    const float* W2   = (const float*)d_in[4];
    const float* b2   = (const float*)d_in[5];
    const float* Wff1 = (const float*)d_in[6];
    const float* bff1 = (const float*)d_in[7];
    const float* Wff2 = (const float*)d_in[8];
    const float* bff2 = (const float*)d_in[9];
    const float* Wta  = (const float*)d_in[10];
    const float* bta  = (const float*)d_in[11];
    const float* Wtb  = (const float*)d_in[12];
    const float* btb  = (const float*)d_in[13];
    const float* Wout = (const float*)d_in[14];
    const float* bout = (const float*)d_in[15];
    float* out = (float*)d_out;

    _Float16* wf = (_Float16*)d_ws;
    char* act = (char*)d_ws + ACT_OFF;
    int* cnt = (int*)((char*)d_ws + CNT_OFF);

    hipMemsetAsync(cnt, 0, CNT_BYTES, stream);
    prep_weights<<<(NFRAG * 512) / 256, 256, 0, stream>>>(W1, W2, Wff1, Wff2, Wta, Wtb, Wout, wf);
    cfc_main<<<NCLUST * CBLK, 256, 0, stream>>>(x, ts, b1, b2, bff1, bff2, bta, btb, bout,
                                                wf, act, cnt, out);
}

// Round 15
// 2090.290 us; speedup vs baseline: 2.1012x; 1.3633x over previous
//
#include <hip/hip_runtime.h>

typedef _Float16 f16x8 __attribute__((ext_vector_type(8)));
typedef _Float16 f16x4 __attribute__((ext_vector_type(4)));
typedef float    f32x4 __attribute__((ext_vector_type(4)));

#define DEVINL __device__ __forceinline__

namespace {
constexpr int Tt = 256, Ff = 128, Hh = 256, Uu = 512, OUTo = 128;
constexpr int NCLUST = 32;               // 512 / 16 row-groups
constexpr int CBLK = 8;                  // blocks per cluster
constexpr int NSLOT = 68;                // frags per (cb,wave): 12 W1 + 16 W2 + 32 heads + 8 Wout
constexpr int NFRAG = CBLK * 4 * NSLOT;  // 2176
constexpr size_t WFRAG_BYTES = (size_t)NFRAG * 1024;
constexpr size_t ACT_OFF = WFRAG_BYTES;
constexpr size_t ACT_STRIDE = 40960;     // z1 16K | z2 16K | h 8K (+pad)
constexpr size_t CNT_OFF = ACT_OFF + (size_t)NCLUST * ACT_STRIDE;
constexpr size_t CNT_BYTES = (size_t)NCLUST * 8 * 4;   // 8 flag slots per cluster
}

// ---- weight prep: f32 row-major -> per-(cb,wave) fp16 MFMA fragment banks ----
__global__ void prep_weights(const float* __restrict__ W1, const float* __restrict__ W2,
                             const float* __restrict__ Wff1, const float* __restrict__ Wff2,
                             const float* __restrict__ Wta, const float* __restrict__ Wtb,
                             const float* __restrict__ Wout, _Float16* __restrict__ ws)
{
    int o = blockIdx.x * blockDim.x + threadIdx.x;
    if (o >= NFRAG * 512) return;
    int j = o & 7, l = (o >> 3) & 63, r = o >> 9;
    int slot = r % NSLOT, bw = r / NSLOT;
    int w = bw & 3, cb = bw >> 2;
    int k_in = ((l >> 4) << 3) + j, lc = l & 15;
    float v;
    if (slot < 12) {
        int kt = slot;
        v = W1[(kt * 32 + k_in) * Uu + cb * 64 + w * 16 + lc];
    } else if (slot < 28) {
        int kt = slot - 12;
        v = W2[(kt * 32 + k_in) * Uu + cb * 64 + w * 16 + lc];
    } else if (slot < 60) {
        int s = slot - 28, hpL = s >> 4, kt = s & 15;
        int head = (w & 1) * 2 + hpL;
        const float* W = (head == 0) ? Wff1 : (head == 1) ? Wff2 : (head == 2) ? Wta : Wtb;
        v = W[(kt * 32 + k_in) * Hh + cb * 32 + (w >> 1) * 16 + lc];
    } else {
        int kt = slot - 60;
        v = Wout[(kt * 32 + k_in) * OUTo + cb * 16 + lc];
    }
    ws[o] = (_Float16)v;
}

DEVINL float fast_tanh(float v) {
    float e = __expf(2.0f * v);
    return 1.0f - 2.0f / (e + 1.0f);
}
DEVINL float fast_sigmoid(float v) { return 1.0f / (1.0f + __expf(-v)); }
DEVINL float lecun_act(float v)    { return 1.7159f * fast_tanh(0.666f * v); }

// ---- device-scope (sc1) accessors ----
DEVINL void stg8_dev(_Float16* p, f16x4 v) {
    asm volatile("global_store_dwordx2 %0, %1, off sc1" :: "v"(p), "v"(v) : "memory");
}

// cooperative tile gathers (fully coalesced, one pass per block)
#define GATHER4(g0, g1, g2, g3, base) \
    asm volatile( \
        "global_load_dwordx4 %0, %4, off sc1\n\t" \
        "global_load_dwordx4 %1, %5, off sc1\n\t" \
        "global_load_dwordx4 %2, %6, off sc1\n\t" \
        "global_load_dwordx4 %3, %7, off sc1\n\t" \
        "s_waitcnt vmcnt(0)" \
        : "=&v"(g0), "=&v"(g1), "=&v"(g2), "=&v"(g3) \
        : "v"(base), "v"((base) + 4096), "v"((base) + 8192), "v"((base) + 12288) \
        : "memory")

#define GATHER2(g0, g1, base) \
    asm volatile( \
        "global_load_dwordx4 %0, %2, off sc1\n\t" \
        "global_load_dwordx4 %1, %3, off sc1\n\t" \
        "s_waitcnt vmcnt(0)" \
        : "=&v"(g0), "=&v"(g1) \
        : "v"(base), "v"((base) + 4096) \
        : "memory")

#define MFMA16(a, b, c) __builtin_amdgcn_mfma_f32_16x16x32_f16(a, b, c, 0, 0, 0)

// arrive: drain all my stores, block-sync, thread0 publishes monotone tag (device scope)
DEVINL void arrive(int* flags, int cb, int tag, int tid) {
    asm volatile("s_waitcnt vmcnt(0)" ::: "memory");
    __syncthreads();
    if (tid == 0)
        asm volatile("global_store_dword %0, %1, off sc1" :: "v"(flags + cb), "v"(tag) : "memory");
}
// wait: thread0 polls all 8 flags >= tag
DEVINL void waitf(int* flags, int tag, int tid) {
    if (tid == 0) {
        for (;;) {
            int4 a, b;
            asm volatile("global_load_dwordx4 %0, %2, off sc1\n\t"
                         "global_load_dwordx4 %1, %2, off offset:16 sc1\n\t"
                         "s_waitcnt vmcnt(0)"
                         : "=&v"(a), "=&v"(b) : "v"(flags) : "memory");
            int m0 = min(min(a.x, a.y), min(a.z, a.w));
            int m1 = min(min(b.x, b.y), min(b.z, b.w));
            if (min(m0, m1) >= tag) break;
        }
    }
    __syncthreads();
    __builtin_amdgcn_sched_barrier(0);
}

__global__ __launch_bounds__(256, 1)
void cfc_main(const float* __restrict__ x, const float* __restrict__ ts,
              const float* __restrict__ b1g, const float* __restrict__ b2g,
              const float* __restrict__ bff1g, const float* __restrict__ bff2g,
              const float* __restrict__ btag, const float* __restrict__ btbg,
              const float* __restrict__ boutg,
              const _Float16* __restrict__ wsf,
              char* __restrict__ actbase, int* __restrict__ cntbase,
              float* __restrict__ out)
{
    __shared__ float taL[2][2][2][16][17];            // [t&1][hcol-tile][ta/tb][row][col]
    __shared__ __align__(8) _Float16 xp[4][16][20];   // per-wave transpose tiles
    __shared__ __align__(16) char stg[16 * 1040];     // staged activation tile (padded)

    const int tid = threadIdx.x;
    const int l = tid & 63, w = tid >> 6;             // 4 waves
    const int lc = l & 15, lg = l >> 4;
    const int xr = l >> 2, xs = l & 3;                // xpose readback row/seg
    const int cluster = blockIdx.x & 31;
    const int cb = blockIdx.x >> 5;
    const int r0 = cluster * 16;

    // ---- weight fragments -> registers ----
    // w1f/w2f (112 regs) in arch VGPRs; whf/wof (160 regs) pinned to AGPRs.
    const _Float16* wb = wsf + ((size_t)(cb * 4 + w) * NSLOT) * 512 + l * 8;
    f16x8 w1f[12], w2f[16], whf[32], wof[8];
#pragma unroll
    for (int s = 0; s < 12; ++s) w1f[s] = *(const f16x8*)(wb + s * 512);
#pragma unroll
    for (int s = 0; s < 16; ++s) w2f[s] = *(const f16x8*)(wb + (12 + s) * 512);
#pragma unroll
    for (int s = 0; s < 32; ++s) whf[s] = *(const f16x8*)(wb + (28 + s) * 512);
#pragma unroll
    for (int s = 0; s < 8; ++s)  wof[s] = *(const f16x8*)(wb + (60 + s) * 512);

    // ---- per-lane biases ----
    const int colU = cb * 64 + w * 16 + lc;
    const int hcol = cb * 32 + (w >> 1) * 16 + lc;
    const int colO = cb * 16 + lc;
    const float b1c = b1g[colU], b2c = b2g[colU];
    const float bf1c = bff1g[hcol], bf2c = bff2g[hcol];
    const float btac = btag[hcol], btbc = btbg[hcol];
    const float boc = boutg[colO];

    char* act = actbase + (size_t)cluster * ACT_STRIDE;
    _Float16* z1g = (_Float16*)act;               // [16][512]
    _Float16* z2g = (_Float16*)(act + 16384);     // [16][512]
    _Float16* hg  = (_Float16*)(act + 32768);     // [16][256]
    int* flags = cntbase + cluster * 8;

    f16x8 hfrag[8];
#pragma unroll
    for (int s = 0; s < 8; ++s) hfrag[s] = f16x8{0,0,0,0,0,0,0,0};

    f16x8 xf[4];
    {
        const float* xr_ = x + ((size_t)(r0 + lc) * Tt + 0) * Ff + lg * 8;
#pragma unroll
        for (int kt = 0; kt < 4; ++kt) {
            f32x4 xa = *(const f32x4*)(xr_ + kt * 32);
            f32x4 xb = *(const f32x4*)(xr_ + kt * 32 + 4);
            f16x8 af;
#pragma unroll
            for (int q = 0; q < 4; ++q) { af[q] = (_Float16)xa[q]; af[4 + q] = (_Float16)xb[q]; }
            xf[kt] = af;
        }
    }

    for (int t = 0; t < Tt; ++t) {
        // ---- pin weights resident: arch VGPRs for W1/W2, AGPRs for heads/out ----
#pragma unroll
        for (int s = 0; s < 12; ++s) asm volatile("" : "+v"(w1f[s]));
#pragma unroll
        for (int s = 0; s < 16; ++s) asm volatile("" : "+v"(w2f[s]));
#pragma unroll
        for (int s = 0; s < 32; ++s) asm volatile("" : "+a"(whf[s]));
#pragma unroll
        for (int s = 0; s < 8; ++s)  asm volatile("" : "+a"(wof[s]));

        // ---------- P1: z1 = lecun([x|h] @ W1 + b1) ----------
        {
            f32x4 a0 = {0.f,0.f,0.f,0.f}, a1 = {0.f,0.f,0.f,0.f};
            a0 = MFMA16(xf[0], w1f[0], a0);  a1 = MFMA16(xf[1], w1f[1], a1);
            a0 = MFMA16(xf[2], w1f[2], a0);  a1 = MFMA16(xf[3], w1f[3], a1);
            a0 = MFMA16(hfrag[0], w1f[4], a0);  a1 = MFMA16(hfrag[1], w1f[5], a1);
            a0 = MFMA16(hfrag[2], w1f[6], a0);  a1 = MFMA16(hfrag[3], w1f[7], a1);
            a0 = MFMA16(hfrag[4], w1f[8], a0);  a1 = MFMA16(hfrag[5], w1f[9], a1);
            a0 = MFMA16(hfrag[6], w1f[10], a0); a1 = MFMA16(hfrag[7], w1f[11], a1);
#pragma unroll
            for (int i = 0; i < 4; ++i)
                xp[w][lg * 4 + i][lc] = (_Float16)lecun_act(a0[i] + a1[i] + b1c);
            asm volatile("s_waitcnt lgkmcnt(0)" ::: "memory");
            __builtin_amdgcn_sched_barrier(0);
            f16x4 v = *(const f16x4*)&xp[w][xr][xs * 4];
            stg8_dev(z1g + xr * Uu + cb * 64 + w * 16 + xs * 4, v);
        }
        arrive(flags, cb, 3 * t + 1, tid);

        // ---------- P2: z2 = lecun(z1 @ W2 + b2), staged gather ----------
        waitf(flags, 3 * t + 1, tid);
        {
            {   // cooperative 16KB gather -> LDS (coalesced 16B/lane)
                const char* gz = (const char*)z1g + tid * 16;
                int4 g0, g1, g2, g3;
                GATHER4(g0, g1, g2, g3, gz);
                const int rw = tid >> 6, cwb = (tid & 63) * 16;
                *(int4*)(stg + (rw + 0) * 1040 + cwb) = g0;
                *(int4*)(stg + (rw + 4) * 1040 + cwb) = g1;
                *(int4*)(stg + (rw + 8) * 1040 + cwb) = g2;
                *(int4*)(stg + (rw + 12) * 1040 + cwb) = g3;
            }
            __syncthreads();
            f32x4 a0 = {0.f,0.f,0.f,0.f}, a1 = {0.f,0.f,0.f,0.f};
#pragma unroll
            for (int kt = 0; kt < 16; ++kt) {
                f16x8 zf = *(const f16x8*)(stg + lc * 1040 + kt * 64 + lg * 16);
                if (kt & 1) a1 = MFMA16(zf, w2f[kt], a1);
                else        a0 = MFMA16(zf, w2f[kt], a0);
            }
#pragma unroll
            for (int i = 0; i < 4; ++i)
                xp[w][lg * 4 + i][lc] = (_Float16)lecun_act(a0[i] + a1[i] + b2c);
            asm volatile("s_waitcnt lgkmcnt(0)" ::: "memory");
            __builtin_amdgcn_sched_barrier(0);
            f16x4 v = *(const f16x4*)&xp[w][xr][xs * 4];
            stg8_dev(z2g + xr * Uu + cb * 64 + w * 16 + xs * 4, v);
        }
        arrive(flags, cb, 3 * t + 2, tid);

        // ---------- P3: heads + gate -> h(t), staged gather ----------
        waitf(flags, 3 * t + 2, tid);
        {
            {
                const char* gz = (const char*)z2g + tid * 16;
                int4 g0, g1, g2, g3;
                GATHER4(g0, g1, g2, g3, gz);
                const int rw = tid >> 6, cwb = (tid & 63) * 16;
                *(int4*)(stg + (rw + 0) * 1040 + cwb) = g0;
                *(int4*)(stg + (rw + 4) * 1040 + cwb) = g1;
                *(int4*)(stg + (rw + 8) * 1040 + cwb) = g2;
                *(int4*)(stg + (rw + 12) * 1040 + cwb) = g3;
            }
            __syncthreads();
            f32x4 h0 = {0.f,0.f,0.f,0.f}, h1 = {0.f,0.f,0.f,0.f};
#pragma unroll
            for (int kt = 0; kt < 16; ++kt) {
                f16x8 zf = *(const f16x8*)(stg + lc * 1040 + kt * 64 + lg * 16);
                h0 = MFMA16(zf, whf[kt], h0);
                h1 = MFMA16(zf, whf[16 + kt], h1);
            }
            if (w & 1) {          // heads 2,3 = ta, tb -> LDS (parity double-buffered)
#pragma unroll
                for (int i = 0; i < 4; ++i) {
                    taL[t & 1][w >> 1][0][lg * 4 + i][lc] = h0[i] + btac;
                    taL[t & 1][w >> 1][1][lg * 4 + i][lc] = h1[i] + btbc;
                }
            }
            __syncthreads();
            if (!(w & 1)) {       // heads 0,1 = ff1, ff2 + gate + h store
#pragma unroll
                for (int i = 0; i < 4; ++i) {
                    int row = lg * 4 + i;
                    float tsv = ts[(size_t)(r0 + row) * Tt + t];
                    float ff1 = fast_tanh(h0[i] + bf1c);
                    float ff2 = fast_tanh(h1[i] + bf2c);
                    float ta = taL[t & 1][w >> 1][0][row][lc];
                    float tb = taL[t & 1][w >> 1][1][row][lc];
                    float s = fast_sigmoid(ta * (tsv * (1.0f / 256.0f)) + tb);
                    xp[w][row][lc] = (_Float16)(ff1 + s * (ff2 - ff1));
                }
                asm volatile("s_waitcnt lgkmcnt(0)" ::: "memory");
                __builtin_amdgcn_sched_barrier(0);
                f16x4 v = *(const f16x4*)&xp[w][xr][xs * 4];
                stg8_dev(hg + xr * Hh + cb * 32 + (w >> 1) * 16 + xs * 4, v);
            }
        }
        arrive(flags, cb, 3 * t + 3, tid);

        // ---------- P4: staged h gather; x(t+1) prefetch; out(t) ----------
        waitf(flags, 3 * t + 3, tid);
        {
            f32x4 xa[4], xb[4];
            if (t + 1 < Tt) {
                const float* xr_ = x + ((size_t)(r0 + lc) * Tt + (t + 1)) * Ff + lg * 8;
#pragma unroll
                for (int kt = 0; kt < 4; ++kt) {
                    xa[kt] = *(const f32x4*)(xr_ + kt * 32);
                    xb[kt] = *(const f32x4*)(xr_ + kt * 32 + 4);
                }
            }
            {   // cooperative 8KB gather -> LDS (stride 528)
                const char* gh = (const char*)hg + tid * 16;
                int4 g0, g1;
                GATHER2(g0, g1, gh);
                const int rw = tid >> 5, cwb = (tid & 31) * 16;
                *(int4*)(stg + (rw + 0) * 528 + cwb) = g0;
                *(int4*)(stg + (rw + 8) * 528 + cwb) = g1;
            }
            __syncthreads();
#pragma unroll
            for (int kt = 0; kt < 8; ++kt)
                hfrag[kt] = *(const f16x8*)(stg + lc * 528 + kt * 64 + lg * 16);
            if (t + 1 < Tt) {
#pragma unroll
                for (int kt = 0; kt < 4; ++kt) {
                    f16x8 af;
#pragma unroll
                    for (int q = 0; q < 4; ++q) { af[q] = (_Float16)xa[kt][q]; af[4 + q] = (_Float16)xb[kt][q]; }
                    xf[kt] = af;
                }
            }
            if (w == 0) {
                f32x4 a0 = {0.f,0.f,0.f,0.f}, a1 = {0.f,0.f,0.f,0.f};
                a0 = MFMA16(hfrag[0], wof[0], a0); a1 = MFMA16(hfrag[1], wof[1], a1);
                a0 = MFMA16(hfrag[2], wof[2], a0); a1 = MFMA16(hfrag[3], wof[3], a1);
                a0 = MFMA16(hfrag[4], wof[4], a0); a1 = MFMA16(hfrag[5], wof[5], a1);
                a0 = MFMA16(hfrag[6], wof[6], a0); a1 = MFMA16(hfrag[7], wof[7], a1);
#pragma unroll
                for (int i = 0; i < 4; ++i)
                    out[((size_t)(r0 + lg * 4 + i) * Tt + t) * OUTo + colO] = a0[i] + a1[i] + boc;
            }
        }
    }
}

extern "C" void kernel_launch(void* const* d_in, const int* in_sizes, int n_in,
                              void* d_out, int out_size, void* d_ws, size_t ws_size,
                              hipStream_t stream) {
    const float* x    = (const float*)d_in[0];
    const float* ts   = (const float*)d_in[1];
    const float* W1   = (const float*)d_in[2];
    const float* b1   = (const float*)d_in[3];
    const float* W2   = (const float*)d_in[4];
    const float* b2   = (const float*)d_in[5];
    const float* Wff1 = (const float*)d_in[6];
    const float* bff1 = (const float*)d_in[7];
    const float* Wff2 = (const float*)d_in[8];
    const float* bff2 = (const float*)d_in[9];
    const float* Wta  = (const float*)d_in[10];
    const float* bta  = (const float*)d_in[11];
    const float* Wtb  = (const float*)d_in[12];
    const float* btb  = (const float*)d_in[13];
    const float* Wout = (const float*)d_in[14];
    const float* bout = (const float*)d_in[15];
    float* out = (float*)d_out;

    _Float16* wf = (_Float16*)d_ws;
    char* act = (char*)d_ws + ACT_OFF;
    int* cnt = (int*)((char*)d_ws + CNT_OFF);

    hipMemsetAsync(cnt, 0, CNT_BYTES, stream);
    prep_weights<<<(NFRAG * 512) / 256, 256, 0, stream>>>(W1, W2, Wff1, Wff2, Wta, Wtb, Wout, wf);
    cfc_main<<<NCLUST * CBLK, 256, 0, stream>>>(x, ts, b1, b2, bff1, bff2, bta, btb, bout,
                                                wf, act, cnt, out);
}